// Round 8
// baseline (171.661 us; speedup 1.0000x reference)
//
#include <hip/hip_runtime.h>
#include <math.h>

// Output = segment_softmax over logits that depend ONLY on the inputs part of
// combined @ W_k (the segment-mean MLP contribution is constant within a
// segment and cancels in the segment softmax).
// wx[h][d] = sum_j Wk[d, h*64+j]*Wq[h,j] / 8;  logit[n,h] = x[n,:].wx[h,:];
// per-segment softmax; out[h*N + n].
//
// Round 11:
//  Kernel A: LDS-staged coalesced x reads. One-row-per-thread AoS (160B
//   lane stride) thrashed L1 (32 waves x 10KB >> 32KB) -> repeated L2/L3
//   round trips (R5 FETCH=135MB = 1.7x of x). Now each block stages its
//   256 rows (40KB) via 10 fully-coalesced wave-wide float4 sweeps into
//   LDS (padded 44 words/row, 16B-aligned), then computes from LDS.
//   Every HBM line fetched once; FETCH should drop to ~92MB.
//  Kernel B: block-per-segment (256 thr, 32 waves/CU vs 8 before). Each
//   thread owns <=2 rows in NAMED registers (no runtime-indexed arrays ->
//   no spill; no LDS cache). Two shfl+LDS reductions, 2 barriers.
//   Tail paths for rows>512 are stat-never but correct.

#define NROWS 500000
#define DIM 40
#define NQ (DIM / 4)     // 10 float4 per row
#define NSEG 2048
#define DOTD 64
#define NH 4
#define ABLOCK 256
#define ROWSPB 256       // rows staged per block in A
#define PADW 44          // padded words per row in LDS (16B-aligned slots)

// ---- kernel A: coalesced stage -> LDS, wx fold, boundary scan, logits ----
__global__ __launch_bounds__(ABLOCK) void fused_logits_kernel(
    const float* __restrict__ x,        // [N, 40]
    const int* __restrict__ seg,        // [N], sorted
    const float* __restrict__ Wk,       // [168, 256]
    const float* __restrict__ Wq,       // [4, 64]
    int* __restrict__ seg_start,        // [NSEG]
    int* __restrict__ seg_end,          // [NSEG]
    float4* __restrict__ logit4)        // [NROWS]
{
    __shared__ __align__(16) float xs[ROWSPB * PADW];   // 45056 B
    __shared__ __align__(16) float wxl[NH][DIM];        // 640 B

    const int tid = (int)threadIdx.x;
    const int base = (int)blockIdx.x * ROWSPB;
    const float4* x4 = (const float4*)x;

    // ---- coalesced stage: 10 wave-wide contiguous float4 sweeps ----
    const int g0 = base * NQ;
    const int gend = NROWS * NQ;
    #pragma unroll
    for (int it = 0; it < NQ; ++it) {
        const int g = g0 + it * ABLOCK + tid;
        if (g < gend) {
            const float4 v = x4[g];
            const int loc = it * ABLOCK + tid;     // 0..2559 within block
            const int r = loc / NQ;                // row in block (magic mul)
            const int q = loc - r * NQ;
            *(float4*)&xs[r * PADW + q * 4] = v;   // 16B-aligned slot
        }
    }

    // ---- per-block wx fold (Wk x-part 40KB: L2/L3-resident) ----
    if (tid < DIM * NH) {
        const int h = tid & 3;
        const int d = tid >> 2;
        const float4* wkp = (const float4*)(Wk + d * (NH * DOTD) + h * DOTD);
        const float4* wqp = (const float4*)(Wq + h * DOTD);
        float acc = 0.f;
        #pragma unroll
        for (int j = 0; j < DOTD / 4; ++j) {
            const float4 a = wkp[j];
            const float4 b = wqp[j];
            acc += a.x * b.x + a.y * b.y + a.z * b.z + a.w * b.w;
        }
        wxl[h][d] = acc * 0.125f;                  // fold 1/sqrt(64)
    }
    __syncthreads();

    const int n = base + tid;
    if (n >= NROWS) return;

    // ---- boundary scan with gap fill for empty segments ----
    const int s = seg[n];
    if (n == 0) {
        seg_start[s] = 0;
        for (int t = 0; t < s; ++t) { seg_start[t] = 0; seg_end[t] = 0; }
    } else {
        const int sp = seg[n - 1];
        if (sp != s) {
            seg_start[s] = n;
            seg_end[sp] = n;
            for (int t = sp + 1; t < s; ++t) { seg_start[t] = n; seg_end[t] = n; }
        }
    }
    if (n == NROWS - 1) {
        seg_end[s] = NROWS;
        for (int t = s + 1; t < NSEG; ++t) { seg_start[t] = NROWS; seg_end[t] = NROWS; }
    }

    // ---- logits from LDS row (row-local b128 reads) ----
    float a[NH] = {0.f, 0.f, 0.f, 0.f};
    #pragma unroll
    for (int q = 0; q < NQ; ++q) {
        const float4 v = *(const float4*)&xs[tid * PADW + q * 4];
        #pragma unroll
        for (int h = 0; h < NH; ++h) {
            const float4 w = ((const float4*)wxl[h])[q];   // LDS broadcast
            a[h] += v.x * w.x + v.y * w.y + v.z * w.z + v.w * w.w;
        }
    }
    logit4[n] = make_float4(a[0], a[1], a[2], a[3]);
}

// ---- kernel B: block-per-segment softmax, rows in named registers ----
__global__ __launch_bounds__(ABLOCK) void seg_softmax_kernel(
    const float4* __restrict__ logit4,  // [NROWS]
    const int* __restrict__ seg_start,
    const int* __restrict__ seg_end,
    float* __restrict__ out)            // [4, N]
{
    __shared__ float redm[4][NH];
    __shared__ float reds[4][NH];

    const int tid = (int)threadIdx.x;
    const int s = (int)blockIdx.x;
    const int start = seg_start[s];
    const int rows = seg_end[s] - start;
    if (rows <= 0) return;              // block-uniform exit

    const int lane = tid & 63;
    const int wid = tid >> 6;
    const float4 NEG = make_float4(-3.0e38f, -3.0e38f, -3.0e38f, -3.0e38f);

    // rows i0=tid, i1=tid+256 live in named registers (max seg ~300 < 512)
    const int i0 = tid, i1 = tid + 256;
    const float4 la = (i0 < rows) ? logit4[start + i0] : NEG;
    const float4 lb = (i1 < rows) ? logit4[start + i1] : NEG;

    // ---- max ----
    float lmax[NH] = {fmaxf(la.x, lb.x), fmaxf(la.y, lb.y),
                      fmaxf(la.z, lb.z), fmaxf(la.w, lb.w)};
    for (int i = tid + 512; i < rows; i += ABLOCK) {   // stat-never tail
        const float4 t = logit4[start + i];
        lmax[0] = fmaxf(lmax[0], t.x); lmax[1] = fmaxf(lmax[1], t.y);
        lmax[2] = fmaxf(lmax[2], t.z); lmax[3] = fmaxf(lmax[3], t.w);
    }
    #pragma unroll
    for (int h = 0; h < NH; ++h) {
        float v = lmax[h];
        #pragma unroll
        for (int off = 32; off > 0; off >>= 1) v = fmaxf(v, __shfl_xor(v, off, 64));
        if (lane == 0) redm[wid][h] = v;
    }
    __syncthreads();
    float m[NH];
    #pragma unroll
    for (int h = 0; h < NH; ++h)
        m[h] = fmaxf(fmaxf(redm[0][h], redm[1][h]),
                     fmaxf(redm[2][h], redm[3][h]));

    // ---- sum (exp(-3e38 - m) == 0, so inactive slots add 0) ----
    float lsum[NH] = {
        __expf(la.x - m[0]) + __expf(lb.x - m[0]),
        __expf(la.y - m[1]) + __expf(lb.y - m[1]),
        __expf(la.z - m[2]) + __expf(lb.z - m[2]),
        __expf(la.w - m[3]) + __expf(lb.w - m[3])};
    for (int i = tid + 512; i < rows; i += ABLOCK) {   // stat-never tail
        const float4 t = logit4[start + i];
        lsum[0] += __expf(t.x - m[0]); lsum[1] += __expf(t.y - m[1]);
        lsum[2] += __expf(t.z - m[2]); lsum[3] += __expf(t.w - m[3]);
    }
    #pragma unroll
    for (int h = 0; h < NH; ++h) {
        float v = lsum[h];
        #pragma unroll
        for (int off = 32; off > 0; off >>= 1) v += __shfl_xor(v, off, 64);
        if (lane == 0) reds[wid][h] = v;
    }
    __syncthreads();
    float rden[NH];
    #pragma unroll
    for (int h = 0; h < NH; ++h)
        rden[h] = 1.0f / (reds[0][h] + reds[1][h] + reds[2][h] + reds[3][h]);

    // ---- write (coalesced per h plane) ----
    if (i0 < rows) {
        const int n = start + i0;
        out[(size_t)0 * NROWS + n] = __expf(la.x - m[0]) * rden[0];
        out[(size_t)1 * NROWS + n] = __expf(la.y - m[1]) * rden[1];
        out[(size_t)2 * NROWS + n] = __expf(la.z - m[2]) * rden[2];
        out[(size_t)3 * NROWS + n] = __expf(la.w - m[3]) * rden[3];
    }
    if (i1 < rows) {
        const int n = start + i1;
        out[(size_t)0 * NROWS + n] = __expf(lb.x - m[0]) * rden[0];
        out[(size_t)1 * NROWS + n] = __expf(lb.y - m[1]) * rden[1];
        out[(size_t)2 * NROWS + n] = __expf(lb.z - m[2]) * rden[2];
        out[(size_t)3 * NROWS + n] = __expf(lb.w - m[3]) * rden[3];
    }
    for (int i = tid + 512; i < rows; i += ABLOCK) {   // stat-never tail
        const float4 t = logit4[start + i];
        const int n = start + i;
        out[(size_t)0 * NROWS + n] = __expf(t.x - m[0]) * rden[0];
        out[(size_t)1 * NROWS + n] = __expf(t.y - m[1]) * rden[1];
        out[(size_t)2 * NROWS + n] = __expf(t.z - m[2]) * rden[2];
        out[(size_t)3 * NROWS + n] = __expf(t.w - m[3]) * rden[3];
    }
}

extern "C" void kernel_launch(void* const* d_in, const int* in_sizes, int n_in,
                              void* d_out, int out_size, void* d_ws, size_t ws_size,
                              hipStream_t stream) {
    const float* x  = (const float*)d_in[0];
    const int* seg  = (const int*)d_in[1];
    const float* Wk = (const float*)d_in[11];
    const float* Wq = (const float*)d_in[12];
    float* out = (float*)d_out;

    int* seg_start = (int*)d_ws;                           // [NSEG]
    int* seg_end   = seg_start + NSEG;                     // [NSEG]
    float4* logit4 = (float4*)((char*)d_ws + 16384);       // 16B-aligned, 8 MB

    const int nblk = (NROWS + ROWSPB - 1) / ROWSPB;        // 1954
    hipLaunchKernelGGL(fused_logits_kernel, dim3(nblk), dim3(ABLOCK),
                       0, stream, x, seg, Wk, Wq, seg_start, seg_end, logit4);
    hipLaunchKernelGGL(seg_softmax_kernel, dim3(NSEG), dim3(ABLOCK),
                       0, stream, logit4, seg_start, seg_end, out);
}